// Round 1
// baseline (71.697 us; speedup 1.0000x reference)
//
#include <hip/hip_runtime.h>

#define NPTS   768
#define TPB    256
#define CHUNKS 64            // b-chunks (one block column per chunk)
#define BPB    12            // b rows per block  = NPTS/CHUNKS
#define BPW    3             // b rows per wave   = BPB/4
#define OUTSZ  (NPTS * 16)   // 12288 outputs
#define RSTR   20            // padded red row stride (floats) -> conflict-free

// out[a,i] = sum_b sum_r rbf(d(a,b))[r] * G[b,r,i]
// G[b,r,i] = (1/sqrt(n)) * sum_j W[r,i,j] * f[b,j]   (a-independent factorization)
// Grid: 12 a-groups x 64 b-chunks = 768 blocks. Lane owns one a, acc[16] in regs.
// Partials per chunk go to d_ws; small second kernel reduces 64 chunks.
__global__ __launch_bounds__(TPB) void rbf_main(
        const float* __restrict__ feat,   // [768][16] f32
        const float* __restrict__ geom,   // [768][3]  f32
        const float* __restrict__ Wp,     // [8][16][16] f32
        const float* __restrict__ mup,    // [8] f32
        const float* __restrict__ gmp,    // [8] f32
        const int*   __restrict__ nn,     // [1] int32
        float* __restrict__ partial)      // [CHUNKS][12288] f32 (workspace)
{
    __shared__ __align__(16) float Gs[BPB * 128];        // 6144 B  G chunk
    __shared__ __align__(16) float red[4 * 64 * RSTR];   // 20480 B cross-wave reduce
    __shared__ __align__(16) float fS[BPB * 16];         // 768 B   feat chunk
    __shared__ float gB[BPB * 3];                        // 144 B   b geometry

    const int t    = threadIdx.x;
    const int cid  = blockIdx.x % CHUNKS;
    const int ag   = blockIdx.x / CHUNKS;
    const int b0   = cid * BPB;
    const int lane = t & 63;
    const int w    = t >> 6;
    const int a    = ag * 64 + lane;

    // ---- stage b-side inputs ----
    if (t < BPB * 16) fS[t] = feat[b0 * 16 + t];
    if (t < BPB * 3)  gB[t] = geom[b0 * 3 + t];

    // per-lane a geometry + uniform params (L1-cached scalar loads)
    const float ax = geom[a * 3 + 0];
    const float ay = geom[a * 3 + 1];
    const float az = geom[a * 3 + 2];
    float muv[8], ngv[8];
#pragma unroll
    for (int r = 0; r < 8; ++r) { muv[r] = mup[r]; ngv[r] = -gmp[r]; }
    const float rn = rsqrtf((float)nn[0]);

    __syncthreads();

    // ---- build G chunk: Gs[bb*128 + r*16 + i] = rn * dot(W[r,i,:], f[b0+bb,:]) ----
    // 1536 values, 6 per thread; W rows from L1 (8 KB, hot), f broadcast from LDS.
#pragma unroll
    for (int m = 0; m < 6; ++m) {
        const int idx = t + m * TPB;
        const int bb  = idx >> 7;        // b row
        const int k   = idx & 127;       // r*16 + i
        const float4 f0 = *(const float4*)(fS + bb * 16 + 0);
        const float4 f1 = *(const float4*)(fS + bb * 16 + 4);
        const float4 f2 = *(const float4*)(fS + bb * 16 + 8);
        const float4 f3 = *(const float4*)(fS + bb * 16 + 12);
        const float4 w0 = *(const float4*)(Wp + k * 16 + 0);
        const float4 w1 = *(const float4*)(Wp + k * 16 + 4);
        const float4 w2 = *(const float4*)(Wp + k * 16 + 8);
        const float4 w3 = *(const float4*)(Wp + k * 16 + 12);
        float s = 0.f;
        s = fmaf(f0.x, w0.x, s); s = fmaf(f0.y, w0.y, s);
        s = fmaf(f0.z, w0.z, s); s = fmaf(f0.w, w0.w, s);
        s = fmaf(f1.x, w1.x, s); s = fmaf(f1.y, w1.y, s);
        s = fmaf(f1.z, w1.z, s); s = fmaf(f1.w, w1.w, s);
        s = fmaf(f2.x, w2.x, s); s = fmaf(f2.y, w2.y, s);
        s = fmaf(f2.z, w2.z, s); s = fmaf(f2.w, w2.w, s);
        s = fmaf(f3.x, w3.x, s); s = fmaf(f3.y, w3.y, s);
        s = fmaf(f3.z, w3.z, s); s = fmaf(f3.w, w3.w, s);
        Gs[idx] = s * rn;
    }
    __syncthreads();

    // ---- main contraction: lane = a, wave owns 3 b rows, acc[16] in registers ----
    float acc[16];
#pragma unroll
    for (int i = 0; i < 16; ++i) acc[i] = 0.f;

#pragma unroll
    for (int q = 0; q < BPW; ++q) {
        const int bb = w * BPW + q;
        const float dx = gB[bb * 3 + 0] - ax;
        const float dy = gB[bb * 3 + 1] - ay;
        const float dz = gB[bb * 3 + 2] - az;
        const float d  = sqrtf(fmaf(dx, dx, fmaf(dy, dy, fmaf(dz, dz, 1e-9f))));
        float rbf[8];
#pragma unroll
        for (int r = 0; r < 8; ++r) {
            const float t0 = d - muv[r];
            rbf[r] = __expf(ngv[r] * t0 * t0);
        }
#pragma unroll
        for (int r = 0; r < 8; ++r) {
            // uniform address across lanes -> LDS broadcast, conflict-free
            const float4 g0 = *(const float4*)(Gs + bb * 128 + r * 16 + 0);
            const float4 g1 = *(const float4*)(Gs + bb * 128 + r * 16 + 4);
            const float4 g2 = *(const float4*)(Gs + bb * 128 + r * 16 + 8);
            const float4 g3 = *(const float4*)(Gs + bb * 128 + r * 16 + 12);
            acc[0]  = fmaf(rbf[r], g0.x, acc[0]);  acc[1]  = fmaf(rbf[r], g0.y, acc[1]);
            acc[2]  = fmaf(rbf[r], g0.z, acc[2]);  acc[3]  = fmaf(rbf[r], g0.w, acc[3]);
            acc[4]  = fmaf(rbf[r], g1.x, acc[4]);  acc[5]  = fmaf(rbf[r], g1.y, acc[5]);
            acc[6]  = fmaf(rbf[r], g1.z, acc[6]);  acc[7]  = fmaf(rbf[r], g1.w, acc[7]);
            acc[8]  = fmaf(rbf[r], g2.x, acc[8]);  acc[9]  = fmaf(rbf[r], g2.y, acc[9]);
            acc[10] = fmaf(rbf[r], g2.z, acc[10]); acc[11] = fmaf(rbf[r], g2.w, acc[11]);
            acc[12] = fmaf(rbf[r], g3.x, acc[12]); acc[13] = fmaf(rbf[r], g3.y, acc[13]);
            acc[14] = fmaf(rbf[r], g3.z, acc[14]); acc[15] = fmaf(rbf[r], g3.w, acc[15]);
        }
    }

    // ---- cross-wave reduce (4 partials per a) ----
    float* rrow = red + (w * 64 + lane) * RSTR;   // stride 20: banks spread, <=2-way
#pragma unroll
    for (int i = 0; i < 16; i += 4)
        *(float4*)(rrow + i) = make_float4(acc[i], acc[i + 1], acc[i + 2], acc[i + 3]);
    __syncthreads();

#pragma unroll
    for (int m = 0; m < 4; ++m) {
        const int idx = t + m * TPB;     // idx = al*16 + i over 1024 outputs
        const int al  = idx >> 4;
        const int i   = idx & 15;
        const float s = red[(0 * 64 + al) * RSTR + i]
                      + red[(1 * 64 + al) * RSTR + i]
                      + red[(2 * 64 + al) * RSTR + i]
                      + red[(3 * 64 + al) * RSTR + i];
        partial[cid * OUTSZ + ag * 1024 + idx] = s;   // coalesced
    }
}

// Sum the 64 b-chunk partials. 12288 outputs / 256 = 48 blocks; wave-coalesced reads.
__global__ __launch_bounds__(256) void rbf_reduce(
        const float* __restrict__ partial, float* __restrict__ outp)
{
    const int o = blockIdx.x * 256 + threadIdx.x;
    float s0 = 0.f, s1 = 0.f, s2 = 0.f, s3 = 0.f;
#pragma unroll
    for (int c = 0; c < CHUNKS; c += 4) {
        s0 += partial[(c + 0) * OUTSZ + o];
        s1 += partial[(c + 1) * OUTSZ + o];
        s2 += partial[(c + 2) * OUTSZ + o];
        s3 += partial[(c + 3) * OUTSZ + o];
    }
    outp[o] = (s0 + s1) + (s2 + s3);
}

extern "C" void kernel_launch(void* const* d_in, const int* in_sizes, int n_in,
                              void* d_out, int out_size, void* d_ws, size_t ws_size,
                              hipStream_t stream) {
    const float* feat = (const float*)d_in[0];
    const float* geom = (const float*)d_in[1];
    const float* Wp   = (const float*)d_in[2];
    const float* mup  = (const float*)d_in[3];
    const float* gmp  = (const float*)d_in[4];
    const int*   nn   = (const int*)d_in[5];
    float* outp    = (float*)d_out;
    float* partial = (float*)d_ws;    // 64 * 12288 * 4 B = 3.1 MB << ws_size

    rbf_main<<<dim3(NPTS), dim3(TPB), 0, stream>>>(feat, geom, Wp, mup, gmp, nn, partial);
    rbf_reduce<<<dim3(OUTSZ / 256), dim3(256), 0, stream>>>(partial, outp);
}

// Round 2
// 71.248 us; speedup vs baseline: 1.0063x; 1.0063x over previous
//
#include <hip/hip_runtime.h>

#define NPTS 768
#define TPB  256

// out[a,i] = sum_{b,r,j} rbf(d(a,b))[r]/sqrt(n) * W[r,i,j] * f[b,j]
// One block per output row a (single dispatch). Factor T[r,j] = sum_b rbf[b,r]*f[b,j];
// out = W : T. T-reduction done with in-wave shfl butterfly (no LDS partial matrix).
__global__ __launch_bounds__(TPB) void rbf_conv_kernel(
        const float* __restrict__ feat,   // [768][16] f32
        const float* __restrict__ geom,   // [768][3]  f32
        const float* __restrict__ Wp,     // [8][16][16] f32
        const float* __restrict__ mup,    // [8] f32
        const float* __restrict__ gmp,    // [8] f32
        const int*   __restrict__ nn,     // [1] int32
        float* __restrict__ outp)         // [768][16] f32
{
    // rbf rows: stride 12 floats (48 B) -> phase-2 reads are <=2-way bank aliased (free)
    __shared__ __align__(16) float rbfz[NPTS * 12];   // 36864 B
    __shared__ __align__(16) float Twave[4][128];     // 2048 B  per-wave T partials
    __shared__ float Pp[64];

    const int t = threadIdx.x;
    const int a = blockIdx.x;
    const int w = t >> 6;      // wave id
    const int l = t & 63;      // lane

    const float ax = geom[a * 3 + 0];
    const float ay = geom[a * 3 + 1];
    const float az = geom[a * 3 + 2];
    float muv[8], ngv[8];
#pragma unroll
    for (int r = 0; r < 8; ++r) { muv[r] = mup[r]; ngv[r] = -gmp[r]; }
    const float rn = rsqrtf((float)nn[0]);

    // ---- phase 1: rbf[b][0..7] = exp(-gamma*(d-mu)^2) / sqrt(n) ----
    // geom read straight from L1/L2 (9 KB total) — no staging barrier needed.
    for (int b = t; b < NPTS; b += TPB) {
        const float dx = geom[b * 3 + 0] - ax;
        const float dy = geom[b * 3 + 1] - ay;
        const float dz = geom[b * 3 + 2] - az;
        const float d  = sqrtf(fmaf(dx, dx, fmaf(dy, dy, fmaf(dz, dz, 1e-9f))));
        float e[8];
#pragma unroll
        for (int r = 0; r < 8; ++r) {
            const float t0 = d - muv[r];
            e[r] = __expf(ngv[r] * t0 * t0) * rn;
        }
        *(float4*)(rbfz + b * 12 + 0) = make_float4(e[0], e[1], e[2], e[3]);
        *(float4*)(rbfz + b * 12 + 4) = make_float4(e[4], e[5], e[6], e[7]);
    }
    __syncthreads();   // barrier 1

    // ---- phase 2: T partials in registers. thread (g = t>>2, jq = t&3) ----
    const int jq = t & 3;
    const int g  = t >> 2;
    float acc[8][4];
#pragma unroll
    for (int r = 0; r < 8; ++r)
#pragma unroll
        for (int jj = 0; jj < 4; ++jj) acc[r][jj] = 0.f;

    const float4* feat4 = (const float4*)feat;   // [768][4] float4
#pragma unroll
    for (int k = 0; k < 12; ++k) {
        const int b = g + (k << 6);
        const float4 ra = *(const float4*)(rbfz + b * 12 + 0);  // rbf r=0..3
        const float4 rb = *(const float4*)(rbfz + b * 12 + 4);  // rbf r=4..7
        const float4 fv = feat4[b * 4 + jq];                    // coalesced 1 KB/wave
        const float rr[8] = { ra.x, ra.y, ra.z, ra.w, rb.x, rb.y, rb.z, rb.w };
        const float fj[4] = { fv.x, fv.y, fv.z, fv.w };
#pragma unroll
        for (int r = 0; r < 8; ++r)
#pragma unroll
            for (int jj = 0; jj < 4; ++jj)
                acc[r][jj] = fmaf(rr[r], fj[jj], acc[r][jj]);
    }

    // ---- in-wave butterfly over the 16 g-groups (lane bits 2..5) ----
#pragma unroll
    for (int r = 0; r < 8; ++r)
#pragma unroll
        for (int jj = 0; jj < 4; ++jj) {
            float v = acc[r][jj];
            v += __shfl_xor(v, 4);
            v += __shfl_xor(v, 8);
            v += __shfl_xor(v, 16);
            v += __shfl_xor(v, 32);
            acc[r][jj] = v;   // wave-wide sum for (r, jq*4+jj)
        }

    // lanes 0..3 of each wave hold jq = 0..3 slices; dump 128-float wave partial
    if (l < 4) {
#pragma unroll
        for (int r = 0; r < 8; ++r)
            *(float4*)(&Twave[w][r * 16 + jq * 4]) =
                make_float4(acc[r][0], acc[r][1], acc[r][2], acc[r][3]);
    }
    __syncthreads();   // barrier 2

    // ---- epilogue: out[i] = sum_{r,j} W[r,i,j] * T[r,j],  T = sum of 4 wave partials ----
    if (t < 64) {
        const int i = t & 15, q = t >> 4;
        float s = 0.f;
#pragma unroll
        for (int m = 0; m < 32; ++m) {
            const int rj = q * 32 + m;
            const float tv = Twave[0][rj] + Twave[1][rj] + Twave[2][rj] + Twave[3][rj];
            const int r = rj >> 4, j = rj & 15;
            s = fmaf(Wp[r * 256 + i * 16 + j], tv, s);
        }
        Pp[t] = s;
    }
    __syncthreads();   // barrier 3

    if (t < 16) {
        outp[a * 16 + t] = Pp[t] + Pp[t + 16] + Pp[t + 32] + Pp[t + 48];
    }
}

extern "C" void kernel_launch(void* const* d_in, const int* in_sizes, int n_in,
                              void* d_out, int out_size, void* d_ws, size_t ws_size,
                              hipStream_t stream) {
    const float* feat = (const float*)d_in[0];
    const float* geom = (const float*)d_in[1];
    const float* Wp   = (const float*)d_in[2];
    const float* mup  = (const float*)d_in[3];
    const float* gmp  = (const float*)d_in[4];
    const int*   nn   = (const int*)d_in[5];
    float* outp = (float*)d_out;
    rbf_conv_kernel<<<dim3(NPTS), dim3(TPB), 0, stream>>>(feat, geom, Wp, mup, gmp, nn, outp);
}

// Round 3
// 68.198 us; speedup vs baseline: 1.0513x; 1.0447x over previous
//
#include <hip/hip_runtime.h>

#define NPTS 768
#define TPB  256

// out[a,i] = sum_{b,r,j} rbf(d(a,b))[r]/sqrt(n) * W[r,i,j] * f[b,j]
// One block per output row a. Factor: T[r,j] = sum_b rbf[b,r]*f[b,j]; out = W : T.
// Round-0 structure minus: geom staging barrier, deep reduce, final barrier.
__global__ __launch_bounds__(TPB) void rbf_conv_kernel(
        const float* __restrict__ feat,   // [768][16] f32
        const float* __restrict__ geom,   // [768][3]  f32
        const float* __restrict__ Wp,     // [8][16][16] f32
        const float* __restrict__ mup,    // [8] f32
        const float* __restrict__ gmp,    // [8] f32
        const int*   __restrict__ nn,     // [1] int32
        float* __restrict__ outp)         // [768][16] f32
{
    // zone: phase1/2 = rbf rows (12 floats / 48 B, 2 aligned float4 each)
    //       phase3   = Tp[64][132] f32 partials (33792 B <= 36864 B)
    __shared__ __align__(16) float zone[NPTS * 12];   // 36864 B
    __shared__ __align__(16) float Tc[2][128];        // 1024 B: two 32-deep partial sums
    // total 37.9 KB -> 4 blocks/CU

    const int t = threadIdx.x;
    const int a = blockIdx.x;

    const float ax = geom[a * 3 + 0];
    const float ay = geom[a * 3 + 1];
    const float az = geom[a * 3 + 2];
    float muv[8], ngv[8];
#pragma unroll
    for (int r = 0; r < 8; ++r) { muv[r] = mup[r]; ngv[r] = -gmp[r]; }
    const float rn = rsqrtf((float)nn[0]);

    // ---- phase 1: rbf[b][0..7] = exp(-gamma*(d-mu)^2)/sqrt(n); geom via L1 ----
    for (int b = t; b < NPTS; b += TPB) {
        const float dx = geom[b * 3 + 0] - ax;
        const float dy = geom[b * 3 + 1] - ay;
        const float dz = geom[b * 3 + 2] - az;
        const float d  = sqrtf(fmaf(dx, dx, fmaf(dy, dy, fmaf(dz, dz, 1e-9f))));
        float e[8];
#pragma unroll
        for (int r = 0; r < 8; ++r) {
            const float t0 = d - muv[r];
            e[r] = __expf(ngv[r] * t0 * t0) * rn;
        }
        *(float4*)(zone + b * 12 + 0) = make_float4(e[0], e[1], e[2], e[3]);
        *(float4*)(zone + b * 12 + 4) = make_float4(e[4], e[5], e[6], e[7]);
    }
    __syncthreads();   // barrier 1

    // ---- phase 2: T-partials in registers. thread (g = t>>2, jq = t&3) ----
    const int jq = t & 3;
    const int g  = t >> 2;
    float acc[8][4];
#pragma unroll
    for (int r = 0; r < 8; ++r)
#pragma unroll
        for (int jj = 0; jj < 4; ++jj) acc[r][jj] = 0.f;

    const float4* feat4 = (const float4*)feat;   // [768][4] float4
#pragma unroll
    for (int k = 0; k < 12; ++k) {
        const int b = g + (k << 6);
        const float4 ra = *(const float4*)(zone + b * 12 + 0);  // rbf r=0..3 (quad-broadcast)
        const float4 rb = *(const float4*)(zone + b * 12 + 4);  // rbf r=4..7
        const float4 fv = feat4[b * 4 + jq];                    // coalesced, L1/L2-hot
        const float rr[8] = { ra.x, ra.y, ra.z, ra.w, rb.x, rb.y, rb.z, rb.w };
        const float fj[4] = { fv.x, fv.y, fv.z, fv.w };
#pragma unroll
        for (int r = 0; r < 8; ++r)
#pragma unroll
            for (int jj = 0; jj < 4; ++jj)
                acc[r][jj] = fmaf(rr[r], fj[jj], acc[r][jj]);
    }
    __syncthreads();   // barrier 2: all zone reads done before overwrite

    // ---- phase 3a: spill partials Tp[g][r*16 + jq*4 + jj], row stride 132 ----
    float* Tp = zone;
#pragma unroll
    for (int r = 0; r < 8; ++r) {
        *(float4*)(Tp + g * 132 + r * 16 + jq * 4) =
            make_float4(acc[r][0], acc[r][1], acc[r][2], acc[r][3]);
    }
    __syncthreads();   // barrier 3

    // ---- phase 3b: all 256 threads, depth-32 reduce (lanes: rj consecutive, bank-clean)
    {
        const int rj   = t & 127;
        const int half = t >> 7;
        const float* base = Tp + rj + half * (32 * 132);
        float s = 0.f;
#pragma unroll
        for (int gg = 0; gg < 32; ++gg) s += base[gg * 132];
        Tc[half][rj] = s;
    }
    __syncthreads();   // barrier 4

    // ---- epilogue (wave 0 only): out[i] = sum_{r,j} W[r,i,j] * T[r,j] ----
    if (t < 64) {
        const int i = t & 15, q = t >> 4;
        float s = 0.f;
#pragma unroll
        for (int m = 0; m < 32; ++m) {
            const int rj = q * 32 + m;
            const int r = rj >> 4, j = rj & 15;
            s = fmaf(Wp[r * 256 + i * 16 + j], Tc[0][rj] + Tc[1][rj], s);
        }
        // fold the 4 q-slices inside wave 0: lanes i, i+16, i+32, i+48
        s += __shfl_down(s, 32);
        s += __shfl_down(s, 16);
        if (t < 16) outp[a * 16 + t] = s;
    }
}

extern "C" void kernel_launch(void* const* d_in, const int* in_sizes, int n_in,
                              void* d_out, int out_size, void* d_ws, size_t ws_size,
                              hipStream_t stream) {
    const float* feat = (const float*)d_in[0];
    const float* geom = (const float*)d_in[1];
    const float* Wp   = (const float*)d_in[2];
    const float* mup  = (const float*)d_in[3];
    const float* gmp  = (const float*)d_in[4];
    const int*   nn   = (const int*)d_in[5];
    float* outp = (float*)d_out;
    rbf_conv_kernel<<<dim3(NPTS), dim3(TPB), 0, stream>>>(feat, geom, Wp, mup, gmp, nn, outp);
}